// Round 12
// baseline (200.219 us; speedup 1.0000x reference)
//
#include <hip/hip_runtime.h>
#include <hip/hip_bf16.h>

// C3 partial connection via MFMA (fp16 in / fp32 acc), wave-independent form.
// y = conv5x5(channel-subsets) + bias; out = 1.7159*tanh(2/3*y).
// M = 16 consecutive x-pixels, N = 16 output channels, K = dx*8 + c (c pad 6->8),
// two mfma_f32_16x16x32_f16 per (row, dy): m=0 dx0..3, m=1 dx4 (rest zero-wt).
//
// R12 = R11 + double-width staging: each wave stages 36 px x 16 rows ONCE and
// computes TWO 16-px output tiles sequentially (W6 ring reused -> same register
// class as R11). x-halo 1.25x -> 1.125x; both halves of each 128B output line
// written by the SAME wave (L2 line merge guaranteed). Retained: batched
// staging, 2-wave blocks, setprio, chunked XCD swizzle.

#define IH 142
#define IW 142
#define OH 138
#define OW 138
#define WROWS 12        // output rows per wave (per tile)
#define SROWS 16        // staged input rows per wave
#define SPX   36        // staged px per wave (covers two 16-px tiles + 4 halo)
#define RS_H  288       // halfs per staged row (36 px * 8 ch)
#define RS_D  144       // dwords per staged row
#define WV_HALFS (SROWS * RS_H + 32)  // + zeroed tail pad (m=1 overrun, zero-wt)
#define NTILE_X 5
#define NTILE_Y 6
#define NWG (NTILE_X * NTILE_Y * 256)   // 7680, divisible by 8
#define CPX (NWG / 8)                   // 960 tiles per XCD

typedef _Float16 f16x8 __attribute__((ext_vector_type(8)));
typedef float f32x4 __attribute__((ext_vector_type(4)));

// WIDX[oc][c] = src*64 + block-index, or -1. src 0=w3(6,3,5,5) 1=w4(9,4,5,5)
// 2=w6(1,6,5,5); weight elem = blk*25 + dy*5 + dx.
__device__ __constant__ const short WIDX16[16][6] = {
  {   0,    1,    2,   -1,   -1,   -1},   // oc0  {0,1,2}
  {  -1,    3,    4,    5,   -1,   -1},   // oc1  {1,2,3}
  {  -1,   -1,    6,    7,    8,   -1},   // oc2  {2,3,4}
  {  -1,   -1,   -1,    9,   10,   11},   // oc3  {3,4,5}
  {  12,   -1,   -1,   -1,   13,   14},   // oc4  {0,4,5}
  {  15,   16,   -1,   -1,   -1,   17},   // oc5  {0,1,5}
  {64+0, 64+1, 64+2, 64+3,   -1,   -1},   // oc6  {0,1,2,3}
  {  -1, 64+4, 64+5, 64+6, 64+7,   -1},   // oc7  {1,2,3,4}
  {  -1,   -1, 64+8, 64+9, 64+10, 64+11}, // oc8  {2,3,4,5}
  {64+12,  -1,   -1, 64+13, 64+14, 64+15},// oc9  {0,3,4,5}
  {64+16, 64+17, -1,   -1, 64+18, 64+19}, // oc10 {0,1,4,5}
  {64+20, 64+21, 64+22, -1,  -1, 64+23},  // oc11 {0,1,2,5}
  {64+24, 64+25, -1, 64+26, 64+27,  -1},  // oc12 {0,1,3,4}
  {  -1, 64+28, 64+29, -1, 64+30, 64+31}, // oc13 {1,2,4,5}
  {64+32,  -1, 64+33, 64+34, -1, 64+35},  // oc14 {0,2,3,5}
  {128+0, 128+1, 128+2, 128+3, 128+4, 128+5}, // oc15 {0..5}
};

// prep: per-lane pre-swizzled B fragments, 5 dy x 2 m x 64 lanes x 8 halfs.
__global__ void wprep_kernel(const float* __restrict__ w3, const float* __restrict__ w4,
                             const float* __restrict__ w6, _Float16* __restrict__ tab) {
  int t = blockIdx.x * 256 + threadIdx.x;
  if (t >= 5120) return;
  int j = t & 7, lane = (t >> 3) & 63, dm = t >> 9;
  int dy = dm >> 1, m = dm & 1;
  int q = lane >> 4, oc = lane & 15;
  int k = m * 32 + q * 8 + j;
  int dx = k >> 3, c = k & 7;
  float v = 0.f;
  if (c < 6 && dx < 5) {
    int e = WIDX16[oc][c];
    if (e >= 0) {
      int src = e >> 6, blk = e & 63;
      const float* wp = (src == 0) ? w3 : (src == 1) ? w4 : w6;
      v = wp[blk * 25 + dy * 5 + dx];
    }
  }
  tab[t] = (_Float16)v;
}

__device__ __forceinline__ unsigned int pkh(float a, float b) {
  _Float16 ha = (_Float16)a, hb = (_Float16)b;
  unsigned short ua = __builtin_bit_cast(unsigned short, ha);
  unsigned short ub = __builtin_bit_cast(unsigned short, hb);
  return (unsigned int)ua | ((unsigned int)ub << 16);
}

__device__ __forceinline__ float act(float y) {
  const float TS = 1.9235933878519512f;  // 2*(2/3)*log2(e)
  const float e = __builtin_amdgcn_exp2f(y * TS);
  return fmaf(-2.f * 1.7159f, __builtin_amdgcn_rcpf(e + 1.f), 1.7159f);
}

// Block: 128 threads = 2 independent waves; wave w -> rows y0+w*12..+11,
// 32 px (two sequential 16-px tiles). Logical grid: (5 x-tiles of 32 px,
// 6 y-slabs of 24 rows, 256 images), XCD-chunk-swizzled.
__global__ __launch_bounds__(128, 4)
void c3_mfma(const float* __restrict__ x,
             const float* __restrict__ b3, const float* __restrict__ b4,
             const float* __restrict__ b6, const _Float16* __restrict__ tab,
             float* __restrict__ out) {
  __shared__ __attribute__((aligned(16))) _Float16 sh[2 * WV_HALFS];  // 18560 B

  const int tid  = threadIdx.x;
  const int lane = tid & 63;
  const int w    = tid >> 6;   // 0..1

  // ---- chunked XCD swizzle ----
  const int hwid = (int)blockIdx.x + NTILE_X * ((int)blockIdx.y + NTILE_Y * (int)blockIdx.z);
  const int swz  = (hwid & 7) * CPX + (hwid >> 3);
  const int tx   = swz % NTILE_X;
  const int t2   = swz / NTILE_X;
  const int ty   = t2 % NTILE_Y;
  const int b    = t2 / NTILE_Y;

  const int x0   = min(tx * 32, OW - 32);  // {0,32,64,96,106}
  const int y0   = min(ty * 24, OH - 24);  // {0,24,48,72,96,114}
  const int ry0  = y0 + w * WROWS;         // wave's first row

  const int ocl = lane & 15;
  const int qq  = lane >> 4;

  // ---- staging loads FIRST (critical path): all 36 float2-pairs in flight ----
  // Per-ITEM decode: idx = it*64 + lane over (ic2:4 x row:16 x px2:18) = 1152.
  const float* xb = x + (size_t)b * 6 * IH * IW;

  float2 va[18], vb[18];
  #pragma unroll
  for (int it = 0; it < 18; ++it) {
    const int idx = it * 64 + lane;
    const int ic2 = idx / 288;               // 0..3
    const int rem = idx - ic2 * 288;
    const int row = rem / 18;
    const int px2 = rem - row * 18;
    if (ic2 < 3) {
      const float* pa = xb + ((size_t)(2 * ic2) * IH + (ry0 + row)) * IW + x0 + 2 * px2;
      va[it] = *(const float2*)pa;
      vb[it] = *(const float2*)(pa + (size_t)IH * IW);
    }
  }

  // ---- B fragments + bias (L2-hot; needed only after staging drains) ----
  f16x8 Bf[5][2];
  #pragma unroll
  for (int dy = 0; dy < 5; ++dy)
    #pragma unroll
    for (int m = 0; m < 2; ++m)
      Bf[dy][m] = *(const f16x8*)(tab + ((size_t)((dy * 2 + m) * 64 + lane)) * 8);

  const float bv = (ocl < 6) ? b3[ocl] : (ocl < 15) ? b4[ocl - 6] : b6[0];

  // ---- pack + ds_write (indices recomputed; same per-item predicate) ----
  _Float16* __restrict__ shw = sh + w * WV_HALFS;
  unsigned int* __restrict__ shu = (unsigned int*)shw;
  if (lane < 16) shu[SROWS * RS_D + lane] = 0u;   // zero tail pad

  #pragma unroll
  for (int it = 0; it < 18; ++it) {
    const int idx = it * 64 + lane;
    const int ic2 = idx / 288;
    const int rem = idx - ic2 * 288;
    const int row = rem / 18;
    const int px2 = rem - row * 18;
    const int ha  = row * RS_D + px2 * 8 + ic2;   // dword index
    if (ic2 < 3) {
      shu[ha]     = pkh(va[it].x, vb[it].x);
      shu[ha + 4] = pkh(va[it].y, vb[it].y);
    } else {                                      // pad channels 6,7 -> zero
      shu[ha]     = 0u;
      shu[ha + 4] = 0u;
    }
  }
  // Wave-level LDS visibility: all 64 lanes' ds_writes complete, no barrier.
  asm volatile("s_waitcnt lgkmcnt(0)" ::: "memory");

  const size_t obase = ((size_t)b * 16 + ocl) * OH;

  // ---- two sequential 16-px tiles; W6 ring + C registers reused ----
  #pragma unroll 1
  for (int t = 0; t < 2; ++t) {
    const int voff = (ocl + qq) * 8 + t * 128;    // halfs; +32 for m=1 (dx+4)
    f16x8 W6[6][2];
    #pragma unroll
    for (int i = 0; i < 6; ++i) {
      W6[i][0] = *(const f16x8*)&shw[i * RS_H + voff];
      W6[i][1] = *(const f16x8*)&shw[i * RS_H + voff + 32];
    }

    const int pxb = x0 + t * 16 + qq * 4;
    #pragma unroll
    for (int r = 0; r < WROWS; r += 2) {
      f32x4 C0 = {bv, bv, bv, bv};
      f32x4 C1 = {bv, bv, bv, bv};
      __builtin_amdgcn_s_setprio(1);
      #pragma unroll
      for (int dy = 0; dy < 5; ++dy) {
        const int i0 = (r + dy) % 6;       // compile-time after unroll
        const int i1 = (r + 1 + dy) % 6;
        C0 = __builtin_amdgcn_mfma_f32_16x16x32_f16(W6[i0][0], Bf[dy][0], C0, 0, 0, 0);
        C1 = __builtin_amdgcn_mfma_f32_16x16x32_f16(W6[i1][0], Bf[dy][0], C1, 0, 0, 0);
        C0 = __builtin_amdgcn_mfma_f32_16x16x32_f16(W6[i0][1], Bf[dy][1], C0, 0, 0, 0);
        C1 = __builtin_amdgcn_mfma_f32_16x16x32_f16(W6[i1][1], Bf[dy][1], C1, 0, 0, 0);
      }
      __builtin_amdgcn_s_setprio(0);
      if (r + 2 < WROWS) {  // slide window: rows r+6, r+7
        W6[r % 6][0]       = *(const f16x8*)&shw[(r + 6) * RS_H + voff];
        W6[r % 6][1]       = *(const f16x8*)&shw[(r + 6) * RS_H + voff + 32];
        W6[(r + 1) % 6][0] = *(const f16x8*)&shw[(r + 7) * RS_H + voff];
        W6[(r + 1) % 6][1] = *(const f16x8*)&shw[(r + 7) * RS_H + voff + 32];
      }
      // store rows r, r+1 (always in-bounds: tiles cover OH/OW exactly)
      {
        float* p0 = out + (obase + (ry0 + r)) * OW + pxb;
        float* p1 = p0 + OW;
        *(float2*)p0       = make_float2(act(C0[0]), act(C0[1]));
        *(float2*)(p0 + 2) = make_float2(act(C0[2]), act(C0[3]));
        *(float2*)p1       = make_float2(act(C1[0]), act(C1[1]));
        *(float2*)(p1 + 2) = make_float2(act(C1[2]), act(C1[3]));
      }
    }
  }
}

extern "C" void kernel_launch(void* const* d_in, const int* in_sizes, int n_in,
                              void* d_out, int out_size, void* d_ws, size_t ws_size,
                              hipStream_t stream) {
  const float* x  = (const float*)d_in[0];
  const float* w3 = (const float*)d_in[1];
  const float* b3 = (const float*)d_in[2];
  const float* w4 = (const float*)d_in[3];
  const float* b4 = (const float*)d_in[4];
  const float* w6 = (const float*)d_in[5];
  const float* b6 = (const float*)d_in[6];
  float* out = (float*)d_out;
  _Float16* tab = (_Float16*)d_ws;  // 5120 halfs = 10 KiB

  hipLaunchKernelGGL(wprep_kernel, dim3(20), dim3(256), 0, stream, w3, w4, w6, tab);

  dim3 grid(NTILE_X, NTILE_Y, 256);   // x-tiles (32 px), y-slabs (24 rows), batch
  hipLaunchKernelGGL(c3_mfma, grid, dim3(128), 0, stream, x, b3, b4, b6, tab, out);
}